// Round 1
// baseline (422.665 us; speedup 1.0000x reference)
//
#include <hip/hip_runtime.h>
#include <stdint.h>

#define DD 64      // embedding dim
#define RR 5       // ratings
#define ET 64      // edges per block tile
#define NSG 4      // subgroups of 16 edges per tile
#define NWAVES 5   // one wave per rating r
#define BLOCK (NWAVES * 64)

typedef float f32x4 __attribute__((ext_vector_type(4)));
typedef short short8 __attribute__((ext_vector_type(8)));

__device__ __forceinline__ unsigned short f2bf(float f) {
    union { float f; uint32_t u; } v; v.f = f;
    uint32_t u = v.u;
    u += 0x7FFFu + ((u >> 16) & 1u);   // RNE
    return (unsigned short)(u >> 16);
}
__device__ __forceinline__ float bf2f(unsigned short h) {
    union { uint32_t u; float f; } v; v.u = ((uint32_t)h) << 16;
    return v.f;
}

__launch_bounds__(BLOCK, 4)
__global__ void bilinear_decoder_kernel(
    const float* __restrict__ z_user,
    const float* __restrict__ z_movie,
    const int*   __restrict__ eidx,   // [2, E] int32
    const float* __restrict__ Qm,     // [R, D, D]
    float*       __restrict__ out,    // [E, R]
    int E)
{
    __shared__ alignas(16) unsigned short u_lds[ET][DD + 8]; // stride 72 shorts = 144B (16B-aligned, conflict-friendly)
    __shared__ alignas(16) unsigned short m_lds[ET][DD + 8];
    __shared__ float logit_lds[ET][RR];

    const int tid  = threadIdx.x;
    const int wid  = tid >> 6;      // wave id == rating r
    const int lane = tid & 63;
    const int q    = lane >> 4;     // quarter-wave
    const int lm   = lane & 15;

    // ---- B fragments: Q_r viewed as B[l, k] tiles, register-resident ----
    // mfma_f32_16x16x32_bf16 B layout: col n = lane&15, k = (lane>>4)*8 + j
    // n-tile t: kcol = t*16 + lm ; l-tile s: l = s*32 + q*8 + j
    short8 bfrag[4][2];
    {
        const int r = wid;
        #pragma unroll
        for (int t = 0; t < 4; ++t) {
            const int kcol = t * 16 + lm;
            #pragma unroll
            for (int s = 0; s < 2; ++s) {
                const int l0 = s * 32 + q * 8;
                const float* src = Qm + (((size_t)r * DD + kcol) * DD + l0);
                short8 b;
                #pragma unroll
                for (int j = 0; j < 8; ++j)
                    b[j] = (short)f2bf(src[j]);
                bfrag[t][s] = b;
            }
        }
    }

    const int ntiles = (E + ET - 1) / ET;
    for (int tile = blockIdx.x; tile < ntiles; tile += gridDim.x) {
        const int base = tile * ET;

        // ---- stage gathered u/m rows into LDS as bf16 (coalesced 64-lane row loads) ----
        for (int slot = wid; slot < 2 * ET; slot += NWAVES) {
            const int e = slot & (ET - 1);
            int ge = base + e;
            if (ge >= E) ge = E - 1;           // tail-safe (E % 64 == 0 normally)
            if (slot < ET) {
                const int ri = eidx[ge];
                u_lds[e][lane] = f2bf(z_user[(size_t)ri * DD + lane]);
            } else {
                const int ci = eidx[E + ge];
                m_lds[e][lane] = f2bf(z_movie[(size_t)ci * DD + lane]);
            }
        }
        __syncthreads();

        // ---- each wave: T_r = M * Q_r^T via MFMA, then row-dot with U ----
        #pragma unroll
        for (int g = 0; g < NSG; ++g) {
            // A fragment: row(edge) = lane&15, k(l) = s*32 + q*8 + j  (16B ds_read_b128)
            const int ea = g * 16 + lm;
            short8 afrag[2];
            #pragma unroll
            for (int s = 0; s < 2; ++s)
                afrag[s] = *(const short8*)&m_lds[ea][s * 32 + q * 8];

            f32x4 acc[4];
            #pragma unroll
            for (int t = 0; t < 4; ++t)
                acc[t] = (f32x4){0.f, 0.f, 0.f, 0.f};
            #pragma unroll
            for (int t = 0; t < 4; ++t)
                #pragma unroll
                for (int s = 0; s < 2; ++s)
                    acc[t] = __builtin_amdgcn_mfma_f32_16x16x32_bf16(
                        afrag[s], bfrag[t][s], acc[t], 0, 0, 0);

            // C/D layout: col(k) = lane&15, row(edge) = q*4 + reg  (verified mapping)
            float p[4] = {0.f, 0.f, 0.f, 0.f};
            #pragma unroll
            for (int t = 0; t < 4; ++t) {
                const int k = t * 16 + lm;
                #pragma unroll
                for (int rg = 0; rg < 4; ++rg) {
                    const int e = g * 16 + q * 4 + rg;
                    p[rg] += bf2f(u_lds[e][k]) * acc[t][rg];
                }
            }
            // reduce over the 16 k-lanes (xor bits 0..3 stay within the group)
            #pragma unroll
            for (int off = 1; off < 16; off <<= 1) {
                #pragma unroll
                for (int rg = 0; rg < 4; ++rg)
                    p[rg] += __shfl_xor(p[rg], off);
            }
            if (lm == 0) {
                #pragma unroll
                for (int rg = 0; rg < 4; ++rg)
                    logit_lds[g * 16 + q * 4 + rg][wid] = p[rg];
            }
        }
        __syncthreads();

        // ---- fused log_softmax over r, coalesced 20B/edge store ----
        if (tid < ET) {
            const int ge = base + tid;
            if (ge < E) {
                float l[RR];
                #pragma unroll
                for (int r = 0; r < RR; ++r) l[r] = logit_lds[tid][r];
                float mx = l[0];
                #pragma unroll
                for (int r = 1; r < RR; ++r) mx = fmaxf(mx, l[r]);
                float s = 0.f;
                #pragma unroll
                for (int r = 0; r < RR; ++r) s += __expf(l[r] - mx);
                const float ls = __logf(s);
                float* o = out + (size_t)ge * RR;
                #pragma unroll
                for (int r = 0; r < RR; ++r) o[r] = l[r] - mx - ls;
            }
        }
        __syncthreads();
    }
}

extern "C" void kernel_launch(void* const* d_in, const int* in_sizes, int n_in,
                              void* d_out, int out_size, void* d_ws, size_t ws_size,
                              hipStream_t stream) {
    const float* z_user  = (const float*)d_in[0];
    const float* z_movie = (const float*)d_in[1];
    const int*   eidx    = (const int*)d_in[2];
    const float* Qm      = (const float*)d_in[3];
    float* out = (float*)d_out;

    const int E = in_sizes[2] / 2;
    const int ntiles = (E + ET - 1) / ET;
    int nblocks = ntiles < 2048 ? ntiles : 2048;

    bilinear_decoder_kernel<<<nblocks, BLOCK, 0, stream>>>(
        z_user, z_movie, eidx, Qm, out, E);
}

// Round 2
// 208.055 us; speedup vs baseline: 2.0315x; 2.0315x over previous
//
#include <hip/hip_runtime.h>
#include <stdint.h>

#define DD 64
#define RR 5

typedef float f32x4 __attribute__((ext_vector_type(4)));
typedef short short8 __attribute__((ext_vector_type(8)));

__device__ __forceinline__ unsigned short f2bf(float f) {
    union { float f; uint32_t u; } v; v.f = f;
    uint32_t u = v.u;
    u += 0x7FFFu + ((u >> 16) & 1u);   // RNE
    return (unsigned short)(u >> 16);
}

// One wave owns 16 edges x all 5 ratings. No LDS, no __syncthreads.
//   MFMA: t[k,e] = sum_l Q[r][k][l] * m[e][l]
//     A = Q_r k-tile  (row i = k = lane&15,  l = (lane>>4)*8+j)  -- register-resident bf16
//     B = m rows      (col j = e = lane&15,  l = (lane>>4)*8+j)  -- gathered direct to reg
//     C: col = e = lane&15, row = k_local = (lane>>4)*4+reg      (m89-verified layout)
//   logit[e,r] = sum_k u[e,k]*t[k,e]: 16 fp32 FMAs/lane + shfl_xor(16,32) over k-quarters.
__launch_bounds__(256, 2)
__global__ void bilinear_decoder_kernel(
    const float* __restrict__ z_user,
    const float* __restrict__ z_movie,
    const int*   __restrict__ eidx,   // [2, E]
    const float* __restrict__ Qm,     // [R, D, D]
    float*       __restrict__ out,    // [E, R]
    int E)
{
    const int lane = threadIdx.x & 63;
    const int wid  = threadIdx.x >> 6;
    const int q    = lane >> 4;
    const int lm   = lane & 15;

    // ---- register-resident Q fragments (bf16, A-operand layout), loaded once ----
    // Aq[r][kt][s][j] = Q[r][kt*16+lm][s*32 + q*8 + j]
    short8 Aq[RR][4][2];
#pragma unroll
    for (int r = 0; r < RR; ++r)
#pragma unroll
        for (int kt = 0; kt < 4; ++kt)
#pragma unroll
            for (int s = 0; s < 2; ++s) {
                const float* src = Qm + (((size_t)r * DD + kt * 16 + lm) * DD + s * 32 + q * 8);
                f32x4 a = *(const f32x4*)src;
                f32x4 b = *(const f32x4*)(src + 4);
                short8 h;
#pragma unroll
                for (int j = 0; j < 4; ++j) { h[j] = (short)f2bf(a[j]); h[4 + j] = (short)f2bf(b[j]); }
                Aq[r][kt][s] = h;
            }

    const int ngroups = (E + 15) >> 4;
    const int nw = gridDim.x << 2;
    for (int g = (blockIdx.x << 2) + wid; g < ngroups; g += nw) {
        const int base = g << 4;
        int e = base + lm;
        if (e >= E) e = E - 1;
        const int iu = eidx[e];
        const int im = eidx[E + e];
        const float* __restrict__ ur = z_user  + ((size_t)iu << 6);
        const float* __restrict__ mr = z_movie + ((size_t)im << 6);

        // ---- gather movie row -> bf16 B fragments (2 x 32B/lane, aligned) ----
        short8 Bm[2];
#pragma unroll
        for (int s = 0; s < 2; ++s) {
            f32x4 a = *(const f32x4*)(mr + s * 32 + q * 8);
            f32x4 b = *(const f32x4*)(mr + s * 32 + q * 8 + 4);
            short8 h;
#pragma unroll
            for (int j = 0; j < 4; ++j) { h[j] = (short)f2bf(a[j]); h[4 + j] = (short)f2bf(b[j]); }
            Bm[s] = h;
        }
        // ---- gather user row, fp32 (exactly the C-layout columns this lane needs) ----
        f32x4 uf[4];
#pragma unroll
        for (int kt = 0; kt < 4; ++kt)
            uf[kt] = *(const f32x4*)(ur + kt * 16 + q * 4);

        float lg[RR];
#pragma unroll
        for (int r = 0; r < RR; ++r) {
            f32x4 acc[4];
#pragma unroll
            for (int kt = 0; kt < 4; ++kt) {
                f32x4 c = {0.f, 0.f, 0.f, 0.f};
                c = __builtin_amdgcn_mfma_f32_16x16x32_bf16(Aq[r][kt][0], Bm[0], c, 0, 0, 0);
                c = __builtin_amdgcn_mfma_f32_16x16x32_bf16(Aq[r][kt][1], Bm[1], c, 0, 0, 0);
                acc[kt] = c;
            }
            float p = 0.f;
#pragma unroll
            for (int kt = 0; kt < 4; ++kt)
#pragma unroll
                for (int rg = 0; rg < 4; ++rg)
                    p = fmaf(uf[kt][rg], acc[kt][rg], p);
            // sum over the 4 k-quarters (lane bits 4,5); every lane ends with full logit
            p += __shfl_xor(p, 16);
            p += __shfl_xor(p, 32);
            lg[r] = p;
        }

        // ---- in-register log_softmax over R=5 ----
        float mx = lg[0];
#pragma unroll
        for (int r = 1; r < RR; ++r) mx = fmaxf(mx, lg[r]);
        float sum = 0.f;
#pragma unroll
        for (int r = 0; r < RR; ++r) sum += __expf(lg[r] - mx);
        const float sub = mx + __logf(sum);

        // ---- store: lane(q,lm) writes r=q; q==0 also writes r=4 ----
        if (base + lm < E) {
            const size_t o = (size_t)(base + lm) * RR;
            out[o + q] = lg[q] - sub;
            if (q == 0) out[o + 4] = lg[4] - sub;
        }
    }
}

extern "C" void kernel_launch(void* const* d_in, const int* in_sizes, int n_in,
                              void* d_out, int out_size, void* d_ws, size_t ws_size,
                              hipStream_t stream) {
    const float* z_user  = (const float*)d_in[0];
    const float* z_movie = (const float*)d_in[1];
    const int*   eidx    = (const int*)d_in[2];
    const float* Qm      = (const float*)d_in[3];
    float* out = (float*)d_out;

    const int E = in_sizes[2] / 2;
    const int ngroups = (E + 15) >> 4;
    // 512 blocks x 4 waves = 2048 waves: exactly-resident at 2 waves/SIMD,
    // every wave starts at t=0 and grid-strides ~30 groups (Q reg-load amortized).
    int nblocks = (ngroups + 3) / 4;
    if (nblocks > 512) nblocks = 512;

    bilinear_decoder_kernel<<<nblocks, 256, 0, stream>>>(
        z_user, z_movie, eidx, Qm, out, E);
}

// Round 3
// 179.178 us; speedup vs baseline: 2.3589x; 1.1612x over previous
//
#include <hip/hip_runtime.h>
#include <stdint.h>

#define DD 64
#define RR 5

typedef float f32x4 __attribute__((ext_vector_type(4)));
typedef short short8 __attribute__((ext_vector_type(8)));
typedef __bf16 bf16x8 __attribute__((ext_vector_type(8)));

union BF8 { bf16x8 h; short8 s; };

// two f32x4 -> 8 bf16 (hardware RNE cvt; compiler fuses pairs into v_cvt_pk_bf16_f32)
__device__ __forceinline__ short8 pack_bf16(f32x4 a, f32x4 b) {
    BF8 u;
#pragma unroll
    for (int j = 0; j < 4; ++j) { u.h[j] = (__bf16)a[j]; u.h[4 + j] = (__bf16)b[j]; }
    return u.s;
}

struct Rows {              // named members only (rule #20: no runtime-indexed reg arrays)
    f32x4 m0, m1, m2, m3;  // movie row, raw fp32: m[s*32 + q*8 .. +8] for s=0,1
    f32x4 u0, u1, u2, u3;  // user row, raw fp32: u[kt*16 + q*4 .. +4]
};

// One wave owns 16 edges x all 5 ratings. Q register-resident (asm-pinned).
// 2-deep software pipeline: idx prefetched 2 groups ahead, rows 1 group ahead.
__launch_bounds__(256, 2)
__global__ void bilinear_decoder_kernel(
    const float* __restrict__ z_user,
    const float* __restrict__ z_movie,
    const int*   __restrict__ eidx,   // [2, E]
    const float* __restrict__ Qm,     // [R, D, D]
    float*       __restrict__ out,    // [E, R]
    int E)
{
    const int lane = threadIdx.x & 63;
    const int wid  = threadIdx.x >> 6;
    const int q    = lane >> 4;
    const int lm   = lane & 15;

    __shared__ float st_lds[4][80];   // per-wave store staging (no cross-wave use, no barriers)

    // ---- Q fragments: A-operand layout, bf16, register-resident ----
    // Aq[r][kt][s] = Q[r][kt*16+lm][s*32 + q*8 .. +8]
    short8 Aq[RR][4][2];
#pragma unroll
    for (int r = 0; r < RR; ++r)
#pragma unroll
        for (int kt = 0; kt < 4; ++kt)
#pragma unroll
            for (int s = 0; s < 2; ++s) {
                const float* src = Qm + (((size_t)r * DD + kt * 16 + lm) * DD + s * 32 + q * 8);
                Aq[r][kt][s] = pack_bf16(*(const f32x4*)src, *(const f32x4*)(src + 4));
            }
    // pin: opaque def prevents the compiler from sinking/relolading Q inside the loop
#pragma unroll
    for (int r = 0; r < RR; ++r)
#pragma unroll
        for (int kt = 0; kt < 4; ++kt)
#pragma unroll
            for (int s = 0; s < 2; ++s)
                asm volatile("" : "+v"(Aq[r][kt][s]));

    const int ngroups = (E + 15) >> 4;
    const int nw = gridDim.x << 2;
    const int g0 = (blockIdx.x << 2) + wid;
    if (g0 >= ngroups) return;
    const int nsteps = (ngroups - 1 - g0) / nw + 1;

    // ---- pipeline helpers ----
    auto ld_idx = [&](int g, int& iu, int& im) {
        int gg = g < ngroups ? g : (ngroups - 1);
        int e = (gg << 4) + lm;
        if (e >= E) e = E - 1;
        iu = eidx[e];
        im = eidx[E + e];
    };
    auto ld_rows = [&](int iu, int im, Rows& R_) {
        const float* mr = z_movie + ((size_t)im << 6);
        const float* ur = z_user  + ((size_t)iu << 6);
        R_.m0 = *(const f32x4*)(mr + q * 8);
        R_.m1 = *(const f32x4*)(mr + q * 8 + 4);
        R_.m2 = *(const f32x4*)(mr + 32 + q * 8);
        R_.m3 = *(const f32x4*)(mr + 32 + q * 8 + 4);
        R_.u0 = *(const f32x4*)(ur + q * 4);
        R_.u1 = *(const f32x4*)(ur + 16 + q * 4);
        R_.u2 = *(const f32x4*)(ur + 32 + q * 4);
        R_.u3 = *(const f32x4*)(ur + 48 + q * 4);
    };
    auto compute = [&](const Rows& R_, int g, bool store) {
        const short8 Bm0 = pack_bf16(R_.m0, R_.m1);
        const short8 Bm1 = pack_bf16(R_.m2, R_.m3);
        float lg[RR];
#pragma unroll
        for (int r = 0; r < RR; ++r) {
            float p = 0.f;
#pragma unroll
            for (int kt = 0; kt < 4; ++kt) {
                f32x4 c = {0.f, 0.f, 0.f, 0.f};
                c = __builtin_amdgcn_mfma_f32_16x16x32_bf16(Aq[r][kt][0], Bm0, c, 0, 0, 0);
                c = __builtin_amdgcn_mfma_f32_16x16x32_bf16(Aq[r][kt][1], Bm1, c, 0, 0, 0);
                const f32x4 uf = (kt == 0) ? R_.u0 : (kt == 1) ? R_.u1 : (kt == 2) ? R_.u2 : R_.u3;
#pragma unroll
                for (int rg = 0; rg < 4; ++rg)
                    p = fmaf(uf[rg], c[rg], p);
            }
            p += __shfl_xor(p, 16);   // sum over k-quarters (lane bits 4,5)
            p += __shfl_xor(p, 32);
            lg[r] = p;
        }
        // in-register log_softmax over R=5
        float mx = lg[0];
#pragma unroll
        for (int r = 1; r < RR; ++r) mx = fmaxf(mx, lg[r]);
        float sum = 0.f;
#pragma unroll
        for (int r = 0; r < RR; ++r) sum += __expf(lg[r] - mx);
        const float sub = mx + __logf(sum);

        // stage 80 floats to LDS (static select over q; conflict-free: 5 coprime 32)
        const float v0 = (q == 0) ? lg[0] : (q == 1) ? lg[1] : (q == 2) ? lg[2] : lg[3];
        st_lds[wid][lm * 5 + q] = v0 - sub;
        if (q == 0) st_lds[wid][lm * 5 + 4] = lg[4] - sub;

        if (store) {   // coalesced 320B/group (64B-aligned: g*80*4 = g*320)
            const size_t o = (size_t)g * (16 * RR);
            const size_t lim = (size_t)E * RR;
            if (o + lane < lim)              out[o + lane]      = st_lds[wid][lane];
            if (lane < 16 && o + 64 + lane < lim) out[o + 64 + lane] = st_lds[wid][64 + lane];
        }
    };

    // ---- prologue ----
    int iuA, imA, iuB, imB;
    Rows RA, RB;
    int gA = g0;
    int gB = g0 + nw;
    ld_idx(gA, iuA, imA);
    ld_rows(iuA, imA, RA);      // waits on idx A, issues rows A
    ld_idx(gB, iuB, imB);       // idx B in flight

    // ---- main loop: ping-pong A/B, 2 groups per trip ----
    for (int i = 0; i < nsteps; i += 2) {
        ld_rows(iuB, imB, RB);            // rows for gB (idx B already here)
        ld_idx(gA + 2 * nw, iuA, imA);    // idx for A two steps ahead
        compute(RA, gA, true);            // i < nsteps guaranteed

        ld_rows(iuA, imA, RA);            // rows for next A
        ld_idx(gB + 2 * nw, iuB, imB);    // idx for next B
        compute(RB, gB, (i + 1) < nsteps);

        gA += 2 * nw;
        gB += 2 * nw;
    }
}

extern "C" void kernel_launch(void* const* d_in, const int* in_sizes, int n_in,
                              void* d_out, int out_size, void* d_ws, size_t ws_size,
                              hipStream_t stream) {
    const float* z_user  = (const float*)d_in[0];
    const float* z_movie = (const float*)d_in[1];
    const int*   eidx    = (const int*)d_in[2];
    const float* Qm      = (const float*)d_in[3];
    float* out = (float*)d_out;

    const int E = in_sizes[2] / 2;
    const int ngroups = (E + 15) >> 4;
    // 512 blocks x 4 waves = 2048 waves = 2/SIMD resident (VGPR ~250); every wave
    // starts at t=0 and grid-strides ~30 groups, amortizing the Q register load.
    int nblocks = (ngroups + 3) / 4;
    if (nblocks > 512) nblocks = 512;

    bilinear_decoder_kernel<<<nblocks, 256, 0, stream>>>(
        z_user, z_movie, eidx, Qm, out, E);
}